// Round 11
// baseline (153.768 us; speedup 1.0000x reference)
//
#include <hip/hip_runtime.h>
#include <math.h>

#define B 8
#define T 128
#define I_TOK 196
#define TEXT_DIM 768
#define IMAGE_DIM 1024
#define HIDDEN 512
#define EXP_SCALE 2.88539008177792681f   // 2*log2(e): exp(2x) = 2^(EXP_SCALE*x)

#if __has_builtin(__builtin_amdgcn_exp2f)
#define FAST_EXP2(x) __builtin_amdgcn_exp2f(x)
#else
#define FAST_EXP2(x) exp2f(x)
#endif
#if __has_builtin(__builtin_amdgcn_rcpf)
#define FAST_RCP(x) __builtin_amdgcn_rcpf(x)
#else
#define FAST_RCP(x) __fdividef(1.f, (x))
#endif
#if __has_builtin(__builtin_amdgcn_sched_barrier)
#define SCHED_FENCE() __builtin_amdgcn_sched_barrier(0)
#else
#define SCHED_FENCE()
#endif

typedef short bf16x8 __attribute__((ext_vector_type(8)));
typedef float f32x4 __attribute__((ext_vector_type(4)));

// ---- fragment-tiled layout geometry (R9, unchanged) -----------------------
#define KT_T (TEXT_DIM / 32)
#define KT_I (IMAGE_DIM / 32)
#define MT_T (B * T / 16)
#define MT_I (B * I_TOK / 16)
#define NT   (HIDDEN / 16)

#define XT_ELEMS (MT_T * KT_T * 512)
#define XI_ELEMS (MT_I * KT_I * 512)
#define X_ELEMS  (XT_ELEMS + XI_ELEMS)
#define WT_T_ELEMS (NT * KT_T * 512)
#define W_ELEMS (WT_T_ELEMS + NT * KT_I * 512)

#define XTILES_T (MT_T * KT_T)
#define XTILES   (XTILES_T + MT_I * KT_I)
#define WTILES_T (NT * KT_T)
#define WTILES   (WTILES_T + NT * KT_I)
#define PREP_GRID ((XTILES + WTILES) / 4)

__device__ __forceinline__ unsigned short f2bf(float x) {
    unsigned int u = __float_as_uint(x);
    unsigned int r = u + 0x7FFFu + ((u >> 16) & 1u);   // RNE
    return (unsigned short)(r >> 16);
}
__device__ __forceinline__ float bf2f(unsigned short h) {
    return __uint_as_float(((unsigned int)h) << 16);
}

// ---------------- prep v9 (unchanged) --------------------------------------
__global__ __launch_bounds__(256) void prep_kernel(
        const float* __restrict__ text, const float* __restrict__ image,
        const float* __restrict__ Wt, const float* __restrict__ Wi,
        unsigned short* __restrict__ Xh, unsigned short* __restrict__ Xl,
        unsigned short* __restrict__ WTh, unsigned short* __restrict__ WTl)
{
    const int tid = threadIdx.x;
    const int lane = tid & 63, wv = tid >> 6;
    const int r16 = lane & 15, quad = lane >> 4;
    const int id = blockIdx.x * 4 + wv;

    float v[8];
    unsigned short* oh;
    unsigned short* ol;
    long dst;

    if (id < XTILES) {
        const float* X; int K, mt, kt;
        if (id < XTILES_T) { X = text; K = TEXT_DIM; mt = id / KT_T; kt = id % KT_T; }
        else { const int i2 = id - XTILES_T; X = image; K = IMAGE_DIM; mt = i2 / KT_I; kt = i2 % KT_I; }
        const float* src = X + (long)(mt * 16 + r16) * K + kt * 32 + quad * 8;
        const float4 a = *(const float4*)src;
        const float4 b = *(const float4*)(src + 4);
        v[0]=a.x; v[1]=a.y; v[2]=a.z; v[3]=a.w; v[4]=b.x; v[5]=b.y; v[6]=b.z; v[7]=b.w;
        oh = (id < XTILES_T) ? Xh : Xh + XT_ELEMS;
        ol = (id < XTILES_T) ? Xl : Xl + XT_ELEMS;
        const long tile = (id < XTILES_T) ? id : (long)(id - XTILES_T);
        dst = tile * 512 + lane * 8;
    } else {
        const int idw = id - XTILES;
        const float* W; int K, nt, kt;
        if (idw < WTILES_T) { W = Wt; K = TEXT_DIM; nt = idw / KT_T; kt = idw % KT_T; }
        else { const int i2 = idw - WTILES_T; W = Wi; K = IMAGE_DIM; nt = i2 / KT_I; kt = i2 % KT_I; }
        const float* src = W + (long)(kt * 32 + quad * 8) * HIDDEN + nt * 16 + r16;
        #pragma unroll
        for (int j = 0; j < 8; ++j) v[j] = src[(long)j * HIDDEN];
        oh = (idw < WTILES_T) ? WTh : WTh + WT_T_ELEMS;
        ol = (idw < WTILES_T) ? WTl : WTl + WT_T_ELEMS;
        const long tile = (idw < WTILES_T) ? idw : (long)(idw - WTILES_T);
        dst = tile * 512 + lane * 8;
    }

    uint4 hv, lv;
    unsigned int hh[8], ll[8];
    #pragma unroll
    for (int j = 0; j < 8; ++j) {
        hh[j] = f2bf(v[j]);
        ll[j] = f2bf(v[j] - bf2f((unsigned short)hh[j]));
    }
    hv.x = hh[0] | (hh[1] << 16); hv.y = hh[2] | (hh[3] << 16);
    hv.z = hh[4] | (hh[5] << 16); hv.w = hh[6] | (hh[7] << 16);
    lv.x = ll[0] | (ll[1] << 16); lv.y = ll[2] | (ll[3] << 16);
    lv.z = ll[4] | (ll[5] << 16); lv.w = ll[6] | (ll[7] << 16);
    *(uint4*)(oh + dst) = hv;
    *(uint4*)(ol + dst) = lv;
}

// ---------------- MFMA projections v11 -------------------------------------
// Core identical to R9. Epilogue change: image GEMM now stores the exp2
// values TRANSPOSED as EiT[b][h][i] (196-contiguous in i) so the scores
// kernel's per-h vector load is coalesced. Text GEMM stores pt rows as
// before (consumed as wave-uniform scalars).
#define GT_BLOCKS (32 * 8)
#define GI_BLOCKS (49 * 8)
#define GEMM_GRID (GT_BLOCKS + GI_BLOCKS)
#define PSTRIDE 66
#define EIT_B (HIDDEN * I_TOK)     // 100352 floats per batch

__global__ __launch_bounds__(256, 2) void mfma_proj_kernel(
        const unsigned short* __restrict__ Xh, const unsigned short* __restrict__ Xl,
        const unsigned short* __restrict__ WTh, const unsigned short* __restrict__ WTl,
        const float* __restrict__ bt, const float* __restrict__ bi,
        float* __restrict__ pt, float* __restrict__ EiT)
{
    __shared__ float part[32 * PSTRIDE];

    const int tid = threadIdx.x;
    const int lane = tid & 63, wv = tid >> 6;
    const int r16 = lane & 15, quad = lane >> 4;
    const int nh = wv & 1;
    const int kh = wv >> 1;

    int bid = blockIdx.x;
    const unsigned short *xh, *xl, *wh, *wl; const float* bias;
    int ktiles, is_text;
    if (bid < GT_BLOCKS) {
        xh = Xh; xl = Xl; wh = WTh; wl = WTl; bias = bt; ktiles = KT_T; is_text = 1;
    } else {
        bid -= GT_BLOCKS;
        xh = Xh + XT_ELEMS; xl = Xl + XT_ELEMS;
        wh = WTh + WT_T_ELEMS; wl = WTl + WT_T_ELEMS;
        bias = bi; ktiles = KT_I; is_text = 0;
    }
    const int m0 = (bid >> 3) * 32;
    const int n0 = (bid & 7) * 64 + nh * 32;
    const int nstep = ktiles >> 1;
    const int kt0 = kh * nstep;
    const int mt0 = (bid >> 3) * 2;
    const int nt0 = (bid & 7) * 4 + nh * 2;

    const unsigned short* pa0 = xh + ((long)mt0 * ktiles + kt0) * 512 + lane * 8;
    const unsigned short* pa1 = pa0 + (long)ktiles * 512;
    const unsigned short* qa0 = xl + ((long)mt0 * ktiles + kt0) * 512 + lane * 8;
    const unsigned short* qa1 = qa0 + (long)ktiles * 512;
    const unsigned short* pb0 = wh + ((long)nt0 * ktiles + kt0) * 512 + lane * 8;
    const unsigned short* pb1 = pb0 + (long)ktiles * 512;
    const unsigned short* qb0 = wl + ((long)nt0 * ktiles + kt0) * 512 + lane * 8;
    const unsigned short* qb1 = qb0 + (long)ktiles * 512;

    f32x4 a00 = {0,0,0,0}, a01 = {0,0,0,0}, a10 = {0,0,0,0}, a11 = {0,0,0,0};

    bf16x8 Ah0 = *(const bf16x8*)(pa0);
    bf16x8 Ah1 = *(const bf16x8*)(pa1);
    bf16x8 Al0 = *(const bf16x8*)(qa0);
    bf16x8 Al1 = *(const bf16x8*)(qa1);
    bf16x8 Bh0 = *(const bf16x8*)(pb0);
    bf16x8 Bh1 = *(const bf16x8*)(pb1);
    bf16x8 Bl0 = *(const bf16x8*)(qb0);
    bf16x8 Bl1 = *(const bf16x8*)(qb1);

    for (int s = 0; s < nstep; ++s) {
        const long kn = (s + 1 < nstep) ? (long)(s + 1) * 512 : 0;
        const bf16x8 nAh0 = *(const bf16x8*)(pa0 + kn);
        const bf16x8 nAh1 = *(const bf16x8*)(pa1 + kn);
        const bf16x8 nAl0 = *(const bf16x8*)(qa0 + kn);
        const bf16x8 nAl1 = *(const bf16x8*)(qa1 + kn);
        const bf16x8 nBh0 = *(const bf16x8*)(pb0 + kn);
        const bf16x8 nBh1 = *(const bf16x8*)(pb1 + kn);
        const bf16x8 nBl0 = *(const bf16x8*)(qb0 + kn);
        const bf16x8 nBl1 = *(const bf16x8*)(qb1 + kn);
        SCHED_FENCE();

        a00 = __builtin_amdgcn_mfma_f32_16x16x32_bf16(Ah0, Bh0, a00, 0, 0, 0);
        a01 = __builtin_amdgcn_mfma_f32_16x16x32_bf16(Ah0, Bh1, a01, 0, 0, 0);
        a10 = __builtin_amdgcn_mfma_f32_16x16x32_bf16(Ah1, Bh0, a10, 0, 0, 0);
        a11 = __builtin_amdgcn_mfma_f32_16x16x32_bf16(Ah1, Bh1, a11, 0, 0, 0);
        a00 = __builtin_amdgcn_mfma_f32_16x16x32_bf16(Ah0, Bl0, a00, 0, 0, 0);
        a01 = __builtin_amdgcn_mfma_f32_16x16x32_bf16(Ah0, Bl1, a01, 0, 0, 0);
        a10 = __builtin_amdgcn_mfma_f32_16x16x32_bf16(Ah1, Bl0, a10, 0, 0, 0);
        a11 = __builtin_amdgcn_mfma_f32_16x16x32_bf16(Ah1, Bl1, a11, 0, 0, 0);
        a00 = __builtin_amdgcn_mfma_f32_16x16x32_bf16(Al0, Bh0, a00, 0, 0, 0);
        a01 = __builtin_amdgcn_mfma_f32_16x16x32_bf16(Al0, Bh1, a01, 0, 0, 0);
        a10 = __builtin_amdgcn_mfma_f32_16x16x32_bf16(Al1, Bh0, a10, 0, 0, 0);
        a11 = __builtin_amdgcn_mfma_f32_16x16x32_bf16(Al1, Bh1, a11, 0, 0, 0);
        SCHED_FENCE();

        Ah0 = nAh0; Ah1 = nAh1; Al0 = nAl0; Al1 = nAl1;
        Bh0 = nBh0; Bh1 = nBh1; Bl0 = nBl0; Bl1 = nBl1;
    }

    const int lc = nh * 32 + r16;
    if (kh == 1) {
        #pragma unroll
        for (int r = 0; r < 4; ++r) {
            part[(quad * 4 + r) * PSTRIDE + lc]           = a00[r];
            part[(quad * 4 + r) * PSTRIDE + lc + 16]      = a01[r];
            part[(quad * 4 + 16 + r) * PSTRIDE + lc]      = a10[r];
            part[(quad * 4 + 16 + r) * PSTRIDE + lc + 16] = a11[r];
        }
    }
    __syncthreads();
    if (kh == 0) {
        const float bv0 = bias[n0 + r16];
        const float bv1 = bias[n0 + 16 + r16];
        const int h0 = n0 + r16, h1 = n0 + 16 + r16;
        #pragma unroll
        for (int r = 0; r < 4; ++r) {
            const float v00 = FAST_EXP2((a00[r] + part[(quad * 4 + r) * PSTRIDE + lc]           + bv0) * EXP_SCALE);
            const float v01 = FAST_EXP2((a01[r] + part[(quad * 4 + r) * PSTRIDE + lc + 16]      + bv1) * EXP_SCALE);
            const float v10 = FAST_EXP2((a10[r] + part[(quad * 4 + 16 + r) * PSTRIDE + lc]      + bv0) * EXP_SCALE);
            const float v11 = FAST_EXP2((a11[r] + part[(quad * 4 + 16 + r) * PSTRIDE + lc + 16] + bv1) * EXP_SCALE);
            const int row0 = m0 + quad * 4 + r;
            const int row1 = row0 + 16;
            if (is_text) {
                pt[(long)row0 * HIDDEN + h0] = v00;
                pt[(long)row0 * HIDDEN + h1] = v01;
                pt[(long)row1 * HIDDEN + h0] = v10;
                pt[(long)row1 * HIDDEN + h1] = v11;
            } else {
                const int b0 = row0 / I_TOK, i0 = row0 - b0 * I_TOK;
                const int b1 = row1 / I_TOK, i1 = row1 - b1 * I_TOK;
                EiT[(long)b0 * EIT_B + (long)h0 * I_TOK + i0] = v00;
                EiT[(long)b0 * EIT_B + (long)h1 * I_TOK + i0] = v01;
                EiT[(long)b1 * EIT_B + (long)h0 * I_TOK + i1] = v10;
                EiT[(long)b1 * EIT_B + (long)h1 * I_TOK + i1] = v11;
            }
        }
    }
}

// ---------------- Scores v11 -----------------------------------------------
// Lane = image token i; accumulate over h IN-REGISTER (no cross-lane
// reduction at all). pt[t][h] and wa[h] are wave-uniform -> SGPR operands.
// EiT[b][h][i] load is coalesced across lanes. Per element: fma,rcp,fma.
// Block = (b, t-pair): 512 blocks x 256 thr (threads >=196 masked).
__global__ __launch_bounds__(256) void scores_kernel(const float* __restrict__ pt,
        const float* __restrict__ EiT, const float* __restrict__ wa,
        const float* __restrict__ ba, float* __restrict__ scores)
{
    __shared__ float swa_lds;
    const int tid = threadIdx.x;
    const int b = blockIdx.x >> 6;
    const int t0 = (blockIdx.x & 63) * 2;

    if (tid < 64) {
        float s = 0.f;
        #pragma unroll
        for (int k = 0; k < 8; ++k) s += wa[tid + k * 64];
        #pragma unroll
        for (int off = 32; off; off >>= 1) s += __shfl_xor(s, off);
        if (tid == 0) swa_lds = s;
    }
    __syncthreads();
    const float base = swa_lds + ba[0];

    const int i = (tid < I_TOK) ? tid : (I_TOK - 1);
    const float* eib = EiT + (long)b * EIT_B + i;
    const float* p0 = pt + (long)(b * T + t0) * HIDDEN;
    const float* p1 = p0 + HIDDEN;

    float acc0 = 0.f, acc1 = 0.f;
    #pragma unroll 8
    for (int h = 0; h < HIDDEN; ++h) {
        const float ei = eib[(long)h * I_TOK];   // coalesced vector load
        const float w  = wa[h];                  // scalar
        const float e0 = p0[h];                  // scalar
        const float e1 = p1[h];                  // scalar
        acc0 = fmaf(w, FAST_RCP(fmaf(e0, ei, 1.f)), acc0);
        acc1 = fmaf(w, FAST_RCP(fmaf(e1, ei, 1.f)), acc1);
    }
    if (tid < I_TOK) {
        scores[(long)(b * T + t0)     * I_TOK + tid] = fmaf(-2.f, acc0, base);
        scores[(long)(b * T + t0 + 1) * I_TOK + tid] = fmaf(-2.f, acc1, base);
    }
}

// ---------------- Fused attended outputs (unchanged from R9) ---------------
__global__ __launch_bounds__(256) void att_kernel(const float* __restrict__ scores,
        const float* __restrict__ image, const float* __restrict__ text,
        float* __restrict__ out_text, float* __restrict__ out_img)
{
    const int tid = threadIdx.x, lane = tid & 63, wave = tid >> 6;

    if (blockIdx.x < 512) {
        const int bid = blockIdx.x;
        const int csplit = bid & 1;
        const int grp = bid >> 1;
        const int b = grp >> 5;
        const int t0 = (grp & 31) * 4;

        __shared__ float ps[I_TOK][4];
        {
            const float* srow = scores + ((long)(b * T + t0 + wave)) * I_TOK;
            const float s0 = srow[lane];
            const float s1 = srow[lane + 64];
            const float s2 = srow[lane + 128];
            const float s3 = (lane < 4) ? srow[lane + 192] : -INFINITY;
            float m = fmaxf(fmaxf(s0, s1), fmaxf(s2, s3));
            #pragma unroll
            for (int off = 32; off; off >>= 1) m = fmaxf(m, __shfl_xor(m, off));
            const float e0 = __expf(s0 - m);
            const float e1 = __expf(s1 - m);
            const float e2 = __expf(s2 - m);
            const float e3 = (lane < 4) ? __expf(s3 - m) : 0.f;
            float sum = e0 + e1 + e2 + e3;
            #pragma unroll
            for (int off = 32; off; off >>= 1) sum += __shfl_xor(sum, off);
            const float inv = __fdividef(1.0f, sum);
            ps[lane][wave] = e0 * inv;
            ps[lane + 64][wave] = e1 * inv;
            ps[lane + 128][wave] = e2 * inv;
            if (lane < 4) ps[lane + 192][wave] = e3 * inv;
        }
        __syncthreads();

        const float* img = image + (long)b * I_TOK * IMAGE_DIM + csplit * 512 + tid * 2;
        float a00 = 0.f, a01 = 0.f, a10 = 0.f, a11 = 0.f;
        float a20 = 0.f, a21 = 0.f, a30 = 0.f, a31 = 0.f;

        float2 v0 = *(const float2*)(img + 0 * IMAGE_DIM);
        float2 v1 = *(const float2*)(img + 1 * IMAGE_DIM);
        float2 v2 = *(const float2*)(img + 2 * IMAGE_DIM);
        float2 v3 = *(const float2*)(img + 3 * IMAGE_DIM);
        float4 p0 = *(const float4*)&ps[0][0];
        float4 p1 = *(const float4*)&ps[1][0];
        float4 p2 = *(const float4*)&ps[2][0];
        float4 p3 = *(const float4*)&ps[3][0];

        for (int g = 0; g < 49; ++g) {
            const int ib = (g + 1 < 49) ? (g + 1) * 4 : g * 4;
            const float2 w0 = *(const float2*)(img + (long)(ib + 0) * IMAGE_DIM);
            const float2 w1 = *(const float2*)(img + (long)(ib + 1) * IMAGE_DIM);
            const float2 w2 = *(const float2*)(img + (long)(ib + 2) * IMAGE_DIM);
            const float2 w3 = *(const float2*)(img + (long)(ib + 3) * IMAGE_DIM);
            const float4 r0 = *(const float4*)&ps[ib + 0][0];
            const float4 r1 = *(const float4*)&ps[ib + 1][0];
            const float4 r2 = *(const float4*)&ps[ib + 2][0];
            const float4 r3 = *(const float4*)&ps[ib + 3][0];
            a00 = fmaf(p0.x, v0.x, a00); a01 = fmaf(p0.x, v0.y, a01);
            a10 = fmaf(p0.y, v0.x, a10); a11 = fmaf(p0.y, v0.y, a11);
            a20 = fmaf(p0.z, v0.x, a20); a21 = fmaf(p0.z, v0.y, a21);
            a30 = fmaf(p0.w, v0.x, a30); a31 = fmaf(p0.w, v0.y, a31);
            a00 = fmaf(p1.x, v1.x, a00); a01 = fmaf(p1.x, v1.y, a01);
            a10 = fmaf(p1.y, v1.x, a10); a11 = fmaf(p1.y, v1.y, a11);
            a20 = fmaf(p1.z, v1.x, a20); a21 = fmaf(p1.z, v1.y, a21);
            a30 = fmaf(p1.w, v1.x, a30); a31 = fmaf(p1.w, v1.y, a31);
            a00 = fmaf(p2.x, v2.x, a00); a01 = fmaf(p2.x, v2.y, a01);
            a10 = fmaf(p2.y, v2.x, a10); a11 = fmaf(p2.y, v2.y, a11);
            a20 = fmaf(p2.z, v2.x, a20); a21 = fmaf(p2.z, v2.y, a21);
            a30 = fmaf(p2.w, v2.x, a30); a31 = fmaf(p2.w, v2.y, a31);
            a00 = fmaf(p3.x, v3.x, a00); a01 = fmaf(p3.x, v3.y, a01);
            a10 = fmaf(p3.y, v3.x, a10); a11 = fmaf(p3.y, v3.y, a11);
            a20 = fmaf(p3.z, v3.x, a20); a21 = fmaf(p3.z, v3.y, a21);
            a30 = fmaf(p3.w, v3.x, a30); a31 = fmaf(p3.w, v3.y, a31);
            v0 = w0; v1 = w1; v2 = w2; v3 = w3;
            p0 = r0; p1 = r1; p2 = r2; p3 = r3;
        }
        float* o = out_text + ((long)(b * T + t0)) * IMAGE_DIM + csplit * 512 + tid * 2;
        float2 w;
        w.x = a00; w.y = a01; *(float2*)(o + 0 * IMAGE_DIM) = w;
        w.x = a10; w.y = a11; *(float2*)(o + 1 * IMAGE_DIM) = w;
        w.x = a20; w.y = a21; *(float2*)(o + 2 * IMAGE_DIM) = w;
        w.x = a30; w.y = a31; *(float2*)(o + 3 * IMAGE_DIM) = w;
    } else {
        const int bid = blockIdx.x - 512;
        const int b = bid / (I_TOK / 4);
        const int i0 = (bid % (I_TOK / 4)) * 4;

        __shared__ float qs[T][4];
        {
            const float* sc = scores + (long)b * T * I_TOK + (i0 + wave);
            const float s0 = sc[(long)lane * I_TOK];
            const float s1 = sc[(long)(lane + 64) * I_TOK];
            float m = fmaxf(s0, s1);
            #pragma unroll
            for (int off = 32; off; off >>= 1) m = fmaxf(m, __shfl_xor(m, off));
            const float e0 = __expf(s0 - m);
            const float e1 = __expf(s1 - m);
            float sum = e0 + e1;
            #pragma unroll
            for (int off = 32; off; off >>= 1) sum += __shfl_xor(sum, off);
            const float inv = __fdividef(1.0f, sum);
            qs[lane][wave] = e0 * inv;
            qs[lane + 64][wave] = e1 * inv;
        }
        __syncthreads();

        const float* txt2 = text + (long)b * T * TEXT_DIM + tid * 2;
        const float* txt1 = text + (long)b * T * TEXT_DIM + 512 + tid;
        float a00=0.f,a01=0.f,a02=0.f, a10=0.f,a11=0.f,a12=0.f;
        float a20=0.f,a21=0.f,a22=0.f, a30=0.f,a31=0.f,a32=0.f;

        float2 u0 = *(const float2*)(txt2 + 0 * TEXT_DIM);
        float2 u1 = *(const float2*)(txt2 + 1 * TEXT_DIM);
        float  z0 = txt1[0 * TEXT_DIM];
        float  z1 = txt1[1 * TEXT_DIM];
        float4 q0 = *(const float4*)&qs[0][0];
        float4 q1 = *(const float4*)&qs[1][0];

        for (int g = 0; g < 64; ++g) {
            const int tb = (g + 1 < 64) ? (g + 1) * 2 : g * 2;
            const float2 nu0 = *(const float2*)(txt2 + (long)(tb + 0) * TEXT_DIM);
            const float2 nu1 = *(const float2*)(txt2 + (long)(tb + 1) * TEXT_DIM);
            const float  nz0 = txt1[(long)(tb + 0) * TEXT_DIM];
            const float  nz1 = txt1[(long)(tb + 1) * TEXT_DIM];
            const float4 nq0 = *(const float4*)&qs[tb + 0][0];
            const float4 nq1 = *(const float4*)&qs[tb + 1][0];
            a00 = fmaf(q0.x, u0.x, a00); a01 = fmaf(q0.x, u0.y, a01); a02 = fmaf(q0.x, z0, a02);
            a10 = fmaf(q0.y, u0.x, a10); a11 = fmaf(q0.y, u0.y, a11); a12 = fmaf(q0.y, z0, a12);
            a20 = fmaf(q0.z, u0.x, a20); a21 = fmaf(q0.z, u0.y, a21); a22 = fmaf(q0.z, z0, a22);
            a30 = fmaf(q0.w, u0.x, a30); a31 = fmaf(q0.w, u0.y, a31); a32 = fmaf(q0.w, z0, a32);
            a00 = fmaf(q1.x, u1.x, a00); a01 = fmaf(q1.x, u1.y, a01); a02 = fmaf(q1.x, z1, a02);
            a10 = fmaf(q1.y, u1.x, a10); a11 = fmaf(q1.y, u1.y, a11); a12 = fmaf(q1.y, z1, a12);
            a20 = fmaf(q1.z, u1.x, a20); a21 = fmaf(q1.z, u1.y, a21); a22 = fmaf(q1.z, z1, a22);
            a30 = fmaf(q1.w, u1.x, a30); a31 = fmaf(q1.w, u1.y, a31); a32 = fmaf(q1.w, z1, a32);
            u0 = nu0; u1 = nu1; z0 = nz0; z1 = nz1; q0 = nq0; q1 = nq1;
        }
        float* o = out_img + ((long)b * I_TOK + i0) * TEXT_DIM;
        float2 w;
        w.x = a00; w.y = a01; *(float2*)(o + 0 * TEXT_DIM + tid * 2) = w; o[0 * TEXT_DIM + 512 + tid] = a02;
        w.x = a10; w.y = a11; *(float2*)(o + 1 * TEXT_DIM + tid * 2) = w; o[1 * TEXT_DIM + 512 + tid] = a12;
        w.x = a20; w.y = a21; *(float2*)(o + 2 * TEXT_DIM + tid * 2) = w; o[2 * TEXT_DIM + 512 + tid] = a22;
        w.x = a30; w.y = a31; *(float2*)(o + 3 * TEXT_DIM + tid * 2) = w; o[3 * TEXT_DIM + 512 + tid] = a32;
    }
}

extern "C" void kernel_launch(void* const* d_in, const int* in_sizes, int n_in,
                              void* d_out, int out_size, void* d_ws, size_t ws_size,
                              hipStream_t stream) {
    const float* text  = (const float*)d_in[0];
    const float* image = (const float*)d_in[1];
    const float* Wt    = (const float*)d_in[2];
    const float* bt    = (const float*)d_in[3];
    const float* Wi    = (const float*)d_in[4];
    const float* bi    = (const float*)d_in[5];
    const float* wa    = (const float*)d_in[6];
    const float* ba    = (const float*)d_in[7];

    float* pt  = (float*)d_ws;                      // Et rows [B*T][512]
    float* EiT = pt + (long)B * T * HIDDEN;         // Ei transposed [B][512][196]
    float* sc  = EiT + (long)B * EIT_B;
    unsigned short* Xh  = (unsigned short*)(sc + (long)B * T * I_TOK);
    unsigned short* Xl  = Xh + X_ELEMS;
    unsigned short* WTh = Xl + X_ELEMS;
    unsigned short* WTl = WTh + W_ELEMS;

    float* out_text = (float*)d_out;                        // B*T*IMAGE_DIM
    float* out_img  = out_text + (long)B * T * IMAGE_DIM;   // B*I*TEXT_DIM

    prep_kernel<<<PREP_GRID, 256, 0, stream>>>(text, image, Wt, Wi, Xh, Xl, WTh, WTl);
    mfma_proj_kernel<<<GEMM_GRID, 256, 0, stream>>>(Xh, Xl, WTh, WTl, bt, bi, pt, EiT);
    scores_kernel<<<B * (T / 2), 256, 0, stream>>>(pt, EiT, wa, ba, sc);
    att_kernel<<<512 + B * (I_TOK / 4), 256, 0, stream>>>(sc, image, text, out_text, out_img);
}

// Round 12
// 148.595 us; speedup vs baseline: 1.0348x; 1.0348x over previous
//
#include <hip/hip_runtime.h>
#include <math.h>

#define B 8
#define T 128
#define I_TOK 196
#define TEXT_DIM 768
#define IMAGE_DIM 1024
#define HIDDEN 512
#define EXP_SCALE 2.88539008177792681f   // 2*log2(e): exp(2x) = 2^(EXP_SCALE*x)

#if __has_builtin(__builtin_amdgcn_exp2f)
#define FAST_EXP2(x) __builtin_amdgcn_exp2f(x)
#else
#define FAST_EXP2(x) exp2f(x)
#endif
#if __has_builtin(__builtin_amdgcn_rcpf)
#define FAST_RCP(x) __builtin_amdgcn_rcpf(x)
#else
#define FAST_RCP(x) __fdividef(1.f, (x))
#endif
#if __has_builtin(__builtin_amdgcn_sched_barrier)
#define SCHED_FENCE() __builtin_amdgcn_sched_barrier(0)
#else
#define SCHED_FENCE()
#endif

typedef short bf16x8 __attribute__((ext_vector_type(8)));
typedef float f32x4 __attribute__((ext_vector_type(4)));

// ---- fragment-tiled layout geometry (R9, unchanged) -----------------------
#define KT_T (TEXT_DIM / 32)
#define KT_I (IMAGE_DIM / 32)
#define MT_T (B * T / 16)
#define MT_I (B * I_TOK / 16)
#define NT   (HIDDEN / 16)

#define XT_ELEMS (MT_T * KT_T * 512)
#define XI_ELEMS (MT_I * KT_I * 512)
#define X_ELEMS  (XT_ELEMS + XI_ELEMS)
#define WT_T_ELEMS (NT * KT_T * 512)
#define W_ELEMS (WT_T_ELEMS + NT * KT_I * 512)

#define XTILES_T (MT_T * KT_T)
#define XTILES   (XTILES_T + MT_I * KT_I)
#define WTILES_T (NT * KT_T)
#define WTILES   (WTILES_T + NT * KT_I)
#define PREP_GRID ((XTILES + WTILES) / 4)

__device__ __forceinline__ unsigned short f2bf(float x) {
    unsigned int u = __float_as_uint(x);
    unsigned int r = u + 0x7FFFu + ((u >> 16) & 1u);   // RNE
    return (unsigned short)(r >> 16);
}
__device__ __forceinline__ float bf2f(unsigned short h) {
    return __uint_as_float(((unsigned int)h) << 16);
}

// ---------------- prep v12: coalesced LDS-staged transpose -----------------
// R11 post-mortem: v9 prep read X-tiles at 16 lines/instr and W-tiles at 64
// lines/instr (~1.8M line-requests) -> request-rate bound ~35-40us. v12
// stages through LDS: X read as 2 rows x 32 cols/instr (2 lines), W read as
// 4 k-rows x 16 n/instr (4 lines). Padded LDS (33 / 17) keeps all banked
// accesses <=2-way (free). Fragment output layout byte-identical to v9.
__global__ __launch_bounds__(256) void prep_kernel(
        const float* __restrict__ text, const float* __restrict__ image,
        const float* __restrict__ Wt, const float* __restrict__ Wi,
        unsigned short* __restrict__ Xh, unsigned short* __restrict__ Xl,
        unsigned short* __restrict__ WTh, unsigned short* __restrict__ WTl)
{
    __shared__ float lds[4][544];            // 8.7 KB, one 544-f slice/wave
    const int tid = threadIdx.x;
    const int lane = tid & 63, wv = tid >> 6;
    const int r16 = lane & 15, quad = lane >> 4;
    const int id = blockIdx.x * 4 + wv;
    float* ld = lds[wv];

    unsigned short* oh;
    unsigned short* ol;
    long dst;
    int is_x;

    // ---- stage (coalesced global -> LDS) ----
    if (id < XTILES) {
        is_x = 1;
        const float* X; int K, mt, kt; long tile;
        if (id < XTILES_T) { X = text; K = TEXT_DIM; mt = id / KT_T; kt = id % KT_T;
                             tile = id; oh = Xh; ol = Xl; }
        else { const int i2 = id - XTILES_T; X = image; K = IMAGE_DIM;
               mt = i2 / KT_I; kt = i2 % KT_I; tile = i2;
               oh = Xh + XT_ELEMS; ol = Xl + XT_ELEMS; }
        const int rr = lane >> 5;            // 0..1
        const int cc = lane & 31;            // 0..31
        #pragma unroll
        for (int j = 0; j < 8; ++j) {        // 2 rows x 32 cols per instr
            const int row = j * 2 + rr;
            ld[row * 33 + cc] = X[(long)(mt * 16 + row) * K + kt * 32 + cc];
        }
        dst = tile * 512 + lane * 8;
    } else {
        is_x = 0;
        const int idw = id - XTILES;
        const float* W; int K, nt, kt; long tile;
        if (idw < WTILES_T) { W = Wt; K = TEXT_DIM; nt = idw / KT_T; kt = idw % KT_T;
                              tile = idw; oh = WTh; ol = WTl; }
        else { const int i2 = idw - WTILES_T; W = Wi; K = IMAGE_DIM;
               nt = i2 / KT_I; kt = i2 % KT_I; tile = i2;
               oh = WTh + WT_T_ELEMS; ol = WTl + WT_T_ELEMS; }
        const int kk = lane >> 4;            // 0..3
        const int nn = lane & 15;            // 0..15
        #pragma unroll
        for (int j = 0; j < 8; ++j) {        // 4 k-rows x 16 n per instr
            const int k = j * 4 + kk;
            ld[k * 17 + nn] = W[(long)(kt * 32 + k) * HIDDEN + nt * 16 + nn];
        }
        dst = tile * 512 + lane * 8;
    }
    __syncthreads();

    // ---- read transposed fragment from LDS, convert, coalesced store ----
    float v[8];
    if (is_x) {
        #pragma unroll
        for (int j = 0; j < 8; ++j) v[j] = ld[r16 * 33 + quad * 8 + j];
    } else {
        #pragma unroll
        for (int j = 0; j < 8; ++j) v[j] = ld[(quad * 8 + j) * 17 + r16];
    }

    uint4 hv, lv;
    unsigned int hh[8], ll[8];
    #pragma unroll
    for (int j = 0; j < 8; ++j) {
        hh[j] = f2bf(v[j]);
        ll[j] = f2bf(v[j] - bf2f((unsigned short)hh[j]));
    }
    hv.x = hh[0] | (hh[1] << 16); hv.y = hh[2] | (hh[3] << 16);
    hv.z = hh[4] | (hh[5] << 16); hv.w = hh[6] | (hh[7] << 16);
    lv.x = ll[0] | (ll[1] << 16); lv.y = ll[2] | (ll[3] << 16);
    lv.z = ll[4] | (ll[5] << 16); lv.w = ll[6] | (ll[7] << 16);
    *(uint4*)(oh + dst) = hv;
    *(uint4*)(ol + dst) = lv;
}

// ---------------- MFMA projections v9 (R9 exact) ---------------------------
#define GT_BLOCKS (32 * 8)
#define GI_BLOCKS (49 * 8)
#define GEMM_GRID (GT_BLOCKS + GI_BLOCKS)
#define PSTRIDE 66

__global__ __launch_bounds__(256, 2) void mfma_proj_kernel(
        const unsigned short* __restrict__ Xh, const unsigned short* __restrict__ Xl,
        const unsigned short* __restrict__ WTh, const unsigned short* __restrict__ WTl,
        const float* __restrict__ bt, const float* __restrict__ bi,
        float* __restrict__ pt, float* __restrict__ pi)
{
    __shared__ float part[32 * PSTRIDE];

    const int tid = threadIdx.x;
    const int lane = tid & 63, wv = tid >> 6;
    const int r16 = lane & 15, quad = lane >> 4;
    const int nh = wv & 1;
    const int kh = wv >> 1;

    int bid = blockIdx.x;
    const unsigned short *xh, *xl, *wh, *wl; const float* bias; float* Y;
    int ktiles;
    if (bid < GT_BLOCKS) {
        xh = Xh; xl = Xl; wh = WTh; wl = WTl; bias = bt; Y = pt; ktiles = KT_T;
    } else {
        bid -= GT_BLOCKS;
        xh = Xh + XT_ELEMS; xl = Xl + XT_ELEMS;
        wh = WTh + WT_T_ELEMS; wl = WTl + WT_T_ELEMS;
        bias = bi; Y = pi; ktiles = KT_I;
    }
    const int m0 = (bid >> 3) * 32;
    const int n0 = (bid & 7) * 64 + nh * 32;
    const int nstep = ktiles >> 1;
    const int kt0 = kh * nstep;
    const int mt0 = (bid >> 3) * 2;
    const int nt0 = (bid & 7) * 4 + nh * 2;

    const unsigned short* pa0 = xh + ((long)mt0 * ktiles + kt0) * 512 + lane * 8;
    const unsigned short* pa1 = pa0 + (long)ktiles * 512;
    const unsigned short* qa0 = xl + ((long)mt0 * ktiles + kt0) * 512 + lane * 8;
    const unsigned short* qa1 = qa0 + (long)ktiles * 512;
    const unsigned short* pb0 = wh + ((long)nt0 * ktiles + kt0) * 512 + lane * 8;
    const unsigned short* pb1 = pb0 + (long)ktiles * 512;
    const unsigned short* qb0 = wl + ((long)nt0 * ktiles + kt0) * 512 + lane * 8;
    const unsigned short* qb1 = qb0 + (long)ktiles * 512;

    f32x4 a00 = {0,0,0,0}, a01 = {0,0,0,0}, a10 = {0,0,0,0}, a11 = {0,0,0,0};

    bf16x8 Ah0 = *(const bf16x8*)(pa0);
    bf16x8 Ah1 = *(const bf16x8*)(pa1);
    bf16x8 Al0 = *(const bf16x8*)(qa0);
    bf16x8 Al1 = *(const bf16x8*)(qa1);
    bf16x8 Bh0 = *(const bf16x8*)(pb0);
    bf16x8 Bh1 = *(const bf16x8*)(pb1);
    bf16x8 Bl0 = *(const bf16x8*)(qb0);
    bf16x8 Bl1 = *(const bf16x8*)(qb1);

    for (int s = 0; s < nstep; ++s) {
        const long kn = (s + 1 < nstep) ? (long)(s + 1) * 512 : 0;
        const bf16x8 nAh0 = *(const bf16x8*)(pa0 + kn);
        const bf16x8 nAh1 = *(const bf16x8*)(pa1 + kn);
        const bf16x8 nAl0 = *(const bf16x8*)(qa0 + kn);
        const bf16x8 nAl1 = *(const bf16x8*)(qa1 + kn);
        const bf16x8 nBh0 = *(const bf16x8*)(pb0 + kn);
        const bf16x8 nBh1 = *(const bf16x8*)(pb1 + kn);
        const bf16x8 nBl0 = *(const bf16x8*)(qb0 + kn);
        const bf16x8 nBl1 = *(const bf16x8*)(qb1 + kn);
        SCHED_FENCE();

        a00 = __builtin_amdgcn_mfma_f32_16x16x32_bf16(Ah0, Bh0, a00, 0, 0, 0);
        a01 = __builtin_amdgcn_mfma_f32_16x16x32_bf16(Ah0, Bh1, a01, 0, 0, 0);
        a10 = __builtin_amdgcn_mfma_f32_16x16x32_bf16(Ah1, Bh0, a10, 0, 0, 0);
        a11 = __builtin_amdgcn_mfma_f32_16x16x32_bf16(Ah1, Bh1, a11, 0, 0, 0);
        a00 = __builtin_amdgcn_mfma_f32_16x16x32_bf16(Ah0, Bl0, a00, 0, 0, 0);
        a01 = __builtin_amdgcn_mfma_f32_16x16x32_bf16(Ah0, Bl1, a01, 0, 0, 0);
        a10 = __builtin_amdgcn_mfma_f32_16x16x32_bf16(Ah1, Bl0, a10, 0, 0, 0);
        a11 = __builtin_amdgcn_mfma_f32_16x16x32_bf16(Ah1, Bl1, a11, 0, 0, 0);
        a00 = __builtin_amdgcn_mfma_f32_16x16x32_bf16(Al0, Bh0, a00, 0, 0, 0);
        a01 = __builtin_amdgcn_mfma_f32_16x16x32_bf16(Al0, Bh1, a01, 0, 0, 0);
        a10 = __builtin_amdgcn_mfma_f32_16x16x32_bf16(Al1, Bh0, a10, 0, 0, 0);
        a11 = __builtin_amdgcn_mfma_f32_16x16x32_bf16(Al1, Bh1, a11, 0, 0, 0);
        SCHED_FENCE();

        Ah0 = nAh0; Ah1 = nAh1; Al0 = nAl0; Al1 = nAl1;
        Bh0 = nBh0; Bh1 = nBh1; Bl0 = nBl0; Bl1 = nBl1;
    }

    const int lc = nh * 32 + r16;
    if (kh == 1) {
        #pragma unroll
        for (int r = 0; r < 4; ++r) {
            part[(quad * 4 + r) * PSTRIDE + lc]           = a00[r];
            part[(quad * 4 + r) * PSTRIDE + lc + 16]      = a01[r];
            part[(quad * 4 + 16 + r) * PSTRIDE + lc]      = a10[r];
            part[(quad * 4 + 16 + r) * PSTRIDE + lc + 16] = a11[r];
        }
    }
    __syncthreads();
    if (kh == 0) {
        const int row0 = m0 + quad * 4;
        const float bv0 = bias[n0 + r16];
        const float bv1 = bias[n0 + 16 + r16];
        #pragma unroll
        for (int r = 0; r < 4; ++r) {
            const float v00 = (a00[r] + part[(quad * 4 + r) * PSTRIDE + lc]           + bv0) * EXP_SCALE;
            const float v01 = (a01[r] + part[(quad * 4 + r) * PSTRIDE + lc + 16]      + bv1) * EXP_SCALE;
            const float v10 = (a10[r] + part[(quad * 4 + 16 + r) * PSTRIDE + lc]      + bv0) * EXP_SCALE;
            const float v11 = (a11[r] + part[(quad * 4 + 16 + r) * PSTRIDE + lc + 16] + bv1) * EXP_SCALE;
            Y[(long)(row0 + r)      * HIDDEN + n0 + r16]      = FAST_EXP2(v00);
            Y[(long)(row0 + r)      * HIDDEN + n0 + 16 + r16] = FAST_EXP2(v01);
            Y[(long)(row0 + 16 + r) * HIDDEN + n0 + r16]      = FAST_EXP2(v10);
            Y[(long)(row0 + 16 + r) * HIDDEN + n0 + 16 + r16] = FAST_EXP2(v11);
        }
    }
}

// ---------------- Scores v8 (R9 exact — best measured) ---------------------
__global__ __launch_bounds__(256, 8) void scores_kernel(const float* __restrict__ pt,
        const float* __restrict__ pi, const float* __restrict__ wa,
        const float* __restrict__ ba, float* __restrict__ scores)
{
    const int blk = blockIdx.x;
    const int bt = blk >> 1;
    const int half = blk & 1;
    const int b = bt >> 7;
    const int tid = threadIdx.x;
    const int lane = tid & 63, wave = tid >> 6;

    const float* ptrow = pt + (long)bt * HIDDEN + lane * 8;
    const float4 pA = *(const float4*)ptrow;
    const float4 pB = *(const float4*)(ptrow + 4);
    float4 wA = *(const float4*)(wa + lane * 8);
    float4 wB = *(const float4*)(wa + lane * 8 + 4);

    float S = wA.x + wA.y + wA.z + wA.w + wB.x + wB.y + wB.z + wB.w;
    #pragma unroll
    for (int off = 32; off; off >>= 1) S += __shfl_down(S, off);
    const float base = S + ba[0];

    wA.x *= -2.f; wA.y *= -2.f; wA.z *= -2.f; wA.w *= -2.f;
    wB.x *= -2.f; wB.y *= -2.f; wB.z *= -2.f; wB.w *= -2.f;

    const float* pib = pi + (long)b * I_TOK * HIDDEN + lane * 8;
    const int i0 = half * 98 + wave;
    const int iend = half * 98 + 98;

    float4 ca = *(const float4*)(pib + (long)i0 * HIDDEN);
    float4 cb = *(const float4*)(pib + (long)i0 * HIDDEN + 4);

    for (int i = i0; i < iend; i += 4) {
        const int inx = (i + 4 < iend) ? (i + 4) : i;
        const float4 na = *(const float4*)(pib + (long)inx * HIDDEN);
        const float4 nb = *(const float4*)(pib + (long)inx * HIDDEN + 4);

        float acc = 0.f;
        acc = fmaf(wA.x, FAST_RCP(fmaf(pA.x, ca.x, 1.f)), acc);
        acc = fmaf(wA.y, FAST_RCP(fmaf(pA.y, ca.y, 1.f)), acc);
        acc = fmaf(wA.z, FAST_RCP(fmaf(pA.z, ca.z, 1.f)), acc);
        acc = fmaf(wA.w, FAST_RCP(fmaf(pA.w, ca.w, 1.f)), acc);
        acc = fmaf(wB.x, FAST_RCP(fmaf(pB.x, cb.x, 1.f)), acc);
        acc = fmaf(wB.y, FAST_RCP(fmaf(pB.y, cb.y, 1.f)), acc);
        acc = fmaf(wB.z, FAST_RCP(fmaf(pB.z, cb.z, 1.f)), acc);
        acc = fmaf(wB.w, FAST_RCP(fmaf(pB.w, cb.w, 1.f)), acc);

        #pragma unroll
        for (int off = 32; off; off >>= 1) acc += __shfl_down(acc, off);
        if (lane == 0) scores[(long)bt * I_TOK + i] = base + acc;
        ca = na; cb = nb;
    }
}

// ---------------- Fused attended outputs (R9 exact) ------------------------
__global__ __launch_bounds__(256) void att_kernel(const float* __restrict__ scores,
        const float* __restrict__ image, const float* __restrict__ text,
        float* __restrict__ out_text, float* __restrict__ out_img)
{
    const int tid = threadIdx.x, lane = tid & 63, wave = tid >> 6;

    if (blockIdx.x < 512) {
        const int bid = blockIdx.x;
        const int csplit = bid & 1;
        const int grp = bid >> 1;
        const int b = grp >> 5;
        const int t0 = (grp & 31) * 4;

        __shared__ float ps[I_TOK][4];
        {
            const float* srow = scores + ((long)(b * T + t0 + wave)) * I_TOK;
            const float s0 = srow[lane];
            const float s1 = srow[lane + 64];
            const float s2 = srow[lane + 128];
            const float s3 = (lane < 4) ? srow[lane + 192] : -INFINITY;
            float m = fmaxf(fmaxf(s0, s1), fmaxf(s2, s3));
            #pragma unroll
            for (int off = 32; off; off >>= 1) m = fmaxf(m, __shfl_xor(m, off));
            const float e0 = __expf(s0 - m);
            const float e1 = __expf(s1 - m);
            const float e2 = __expf(s2 - m);
            const float e3 = (lane < 4) ? __expf(s3 - m) : 0.f;
            float sum = e0 + e1 + e2 + e3;
            #pragma unroll
            for (int off = 32; off; off >>= 1) sum += __shfl_xor(sum, off);
            const float inv = __fdividef(1.0f, sum);
            ps[lane][wave] = e0 * inv;
            ps[lane + 64][wave] = e1 * inv;
            ps[lane + 128][wave] = e2 * inv;
            if (lane < 4) ps[lane + 192][wave] = e3 * inv;
        }
        __syncthreads();

        const float* img = image + (long)b * I_TOK * IMAGE_DIM + csplit * 512 + tid * 2;
        float a00 = 0.f, a01 = 0.f, a10 = 0.f, a11 = 0.f;
        float a20 = 0.f, a21 = 0.f, a30 = 0.f, a31 = 0.f;

        float2 v0 = *(const float2*)(img + 0 * IMAGE_DIM);
        float2 v1 = *(const float2*)(img + 1 * IMAGE_DIM);
        float2 v2 = *(const float2*)(img + 2 * IMAGE_DIM);
        float2 v3 = *(const float2*)(img + 3 * IMAGE_DIM);
        float4 p0 = *(const float4*)&ps[0][0];
        float4 p1 = *(const float4*)&ps[1][0];
        float4 p2 = *(const float4*)&ps[2][0];
        float4 p3 = *(const float4*)&ps[3][0];

        for (int g = 0; g < 49; ++g) {
            const int ib = (g + 1 < 49) ? (g + 1) * 4 : g * 4;
            const float2 w0 = *(const float2*)(img + (long)(ib + 0) * IMAGE_DIM);
            const float2 w1 = *(const float2*)(img + (long)(ib + 1) * IMAGE_DIM);
            const float2 w2 = *(const float2*)(img + (long)(ib + 2) * IMAGE_DIM);
            const float2 w3 = *(const float2*)(img + (long)(ib + 3) * IMAGE_DIM);
            const float4 r0 = *(const float4*)&ps[ib + 0][0];
            const float4 r1 = *(const float4*)&ps[ib + 1][0];
            const float4 r2 = *(const float4*)&ps[ib + 2][0];
            const float4 r3 = *(const float4*)&ps[ib + 3][0];
            a00 = fmaf(p0.x, v0.x, a00); a01 = fmaf(p0.x, v0.y, a01);
            a10 = fmaf(p0.y, v0.x, a10); a11 = fmaf(p0.y, v0.y, a11);
            a20 = fmaf(p0.z, v0.x, a20); a21 = fmaf(p0.z, v0.y, a21);
            a30 = fmaf(p0.w, v0.x, a30); a31 = fmaf(p0.w, v0.y, a31);
            a00 = fmaf(p1.x, v1.x, a00); a01 = fmaf(p1.x, v1.y, a01);
            a10 = fmaf(p1.y, v1.x, a10); a11 = fmaf(p1.y, v1.y, a11);
            a20 = fmaf(p1.z, v1.x, a20); a21 = fmaf(p1.z, v1.y, a21);
            a30 = fmaf(p1.w, v1.x, a30); a31 = fmaf(p1.w, v1.y, a31);
            a00 = fmaf(p2.x, v2.x, a00); a01 = fmaf(p2.x, v2.y, a01);
            a10 = fmaf(p2.y, v2.x, a10); a11 = fmaf(p2.y, v2.y, a11);
            a20 = fmaf(p2.z, v2.x, a20); a21 = fmaf(p2.z, v2.y, a21);
            a30 = fmaf(p2.w, v2.x, a30); a31 = fmaf(p2.w, v2.y, a31);
            a00 = fmaf(p3.x, v3.x, a00); a01 = fmaf(p3.x, v3.y, a01);
            a10 = fmaf(p3.y, v3.x, a10); a11 = fmaf(p3.y, v3.y, a11);
            a20 = fmaf(p3.z, v3.x, a20); a21 = fmaf(p3.z, v3.y, a21);
            a30 = fmaf(p3.w, v3.x, a30); a31 = fmaf(p3.w, v3.y, a31);
            v0 = w0; v1 = w1; v2 = w2; v3 = w3;
            p0 = r0; p1 = r1; p2 = r2; p3 = r3;
        }
        float* o = out_text + ((long)(b * T + t0)) * IMAGE_DIM + csplit * 512 + tid * 2;
        float2 w;
        w.x = a00; w.y = a01; *(float2*)(o + 0 * IMAGE_DIM) = w;
        w.x = a10; w.y = a11; *(float2*)(o + 1 * IMAGE_DIM) = w;
        w.x = a20; w.y = a21; *(float2*)(o + 2 * IMAGE_DIM) = w;
        w.x = a30; w.y = a31; *(float2*)(o + 3 * IMAGE_DIM) = w;
    } else {
        const int bid = blockIdx.x - 512;
        const int b = bid / (I_TOK / 4);
        const int i0 = (bid % (I_TOK / 4)) * 4;

        __shared__ float qs[T][4];
        {
            const float* sc = scores + (long)b * T * I_TOK + (i0 + wave);
            const float s0 = sc[(long)lane * I_TOK];
            const float s1 = sc[(long)(lane + 64) * I_TOK];
            float m = fmaxf(s0, s1);
            #pragma unroll
            for (int off = 32; off; off >>= 1) m = fmaxf(m, __shfl_xor(m, off));
            const float e0 = __expf(s0 - m);
            const float e1 = __expf(s1 - m);
            float sum = e0 + e1;
            #pragma unroll
            for (int off = 32; off; off >>= 1) sum += __shfl_xor(sum, off);
            const float inv = __fdividef(1.0f, sum);
            qs[lane][wave] = e0 * inv;
            qs[lane + 64][wave] = e1 * inv;
        }
        __syncthreads();

        const float* txt2 = text + (long)b * T * TEXT_DIM + tid * 2;
        const float* txt1 = text + (long)b * T * TEXT_DIM + 512 + tid;
        float a00=0.f,a01=0.f,a02=0.f, a10=0.f,a11=0.f,a12=0.f;
        float a20=0.f,a21=0.f,a22=0.f, a30=0.f,a31=0.f,a32=0.f;

        float2 u0 = *(const float2*)(txt2 + 0 * TEXT_DIM);
        float2 u1 = *(const float2*)(txt2 + 1 * TEXT_DIM);
        float  z0 = txt1[0 * TEXT_DIM];
        float  z1 = txt1[1 * TEXT_DIM];
        float4 q0 = *(const float4*)&qs[0][0];
        float4 q1 = *(const float4*)&qs[1][0];

        for (int g = 0; g < 64; ++g) {
            const int tb = (g + 1 < 64) ? (g + 1) * 2 : g * 2;
            const float2 nu0 = *(const float2*)(txt2 + (long)(tb + 0) * TEXT_DIM);
            const float2 nu1 = *(const float2*)(txt2 + (long)(tb + 1) * TEXT_DIM);
            const float  nz0 = txt1[(long)(tb + 0) * TEXT_DIM];
            const float  nz1 = txt1[(long)(tb + 1) * TEXT_DIM];
            const float4 nq0 = *(const float4*)&qs[tb + 0][0];
            const float4 nq1 = *(const float4*)&qs[tb + 1][0];
            a00 = fmaf(q0.x, u0.x, a00); a01 = fmaf(q0.x, u0.y, a01); a02 = fmaf(q0.x, z0, a02);
            a10 = fmaf(q0.y, u0.x, a10); a11 = fmaf(q0.y, u0.y, a11); a12 = fmaf(q0.y, z0, a12);
            a20 = fmaf(q0.z, u0.x, a20); a21 = fmaf(q0.z, u0.y, a21); a22 = fmaf(q0.z, z0, a22);
            a30 = fmaf(q0.w, u0.x, a30); a31 = fmaf(q0.w, u0.y, a31); a32 = fmaf(q0.w, z0, a32);
            a00 = fmaf(q1.x, u1.x, a00); a01 = fmaf(q1.x, u1.y, a01); a02 = fmaf(q1.x, z1, a02);
            a10 = fmaf(q1.y, u1.x, a10); a11 = fmaf(q1.y, u1.y, a11); a12 = fmaf(q1.y, z1, a12);
            a20 = fmaf(q1.z, u1.x, a20); a21 = fmaf(q1.z, u1.y, a21); a22 = fmaf(q1.z, z1, a22);
            a30 = fmaf(q1.w, u1.x, a30); a31 = fmaf(q1.w, u1.y, a31); a32 = fmaf(q1.w, z1, a32);
            u0 = nu0; u1 = nu1; z0 = nz0; z1 = nz1; q0 = nq0; q1 = nq1;
        }
        float* o = out_img + ((long)b * I_TOK + i0) * TEXT_DIM;
        float2 w;
        w.x = a00; w.y = a01; *(float2*)(o + 0 * TEXT_DIM + tid * 2) = w; o[0 * TEXT_DIM + 512 + tid] = a02;
        w.x = a10; w.y = a11; *(float2*)(o + 1 * TEXT_DIM + tid * 2) = w; o[1 * TEXT_DIM + 512 + tid] = a12;
        w.x = a20; w.y = a21; *(float2*)(o + 2 * TEXT_DIM + tid * 2) = w; o[2 * TEXT_DIM + 512 + tid] = a22;
        w.x = a30; w.y = a31; *(float2*)(o + 3 * TEXT_DIM + tid * 2) = w; o[3 * TEXT_DIM + 512 + tid] = a32;
    }
}

extern "C" void kernel_launch(void* const* d_in, const int* in_sizes, int n_in,
                              void* d_out, int out_size, void* d_ws, size_t ws_size,
                              hipStream_t stream) {
    const float* text  = (const float*)d_in[0];
    const float* image = (const float*)d_in[1];
    const float* Wt    = (const float*)d_in[2];
    const float* bt    = (const float*)d_in[3];
    const float* Wi    = (const float*)d_in[4];
    const float* bi    = (const float*)d_in[5];
    const float* wa    = (const float*)d_in[6];
    const float* ba    = (const float*)d_in[7];

    float* pt = (float*)d_ws;                       // Et = exp2-transformed
    float* pi = pt + (long)B * T * HIDDEN;          // Ei
    float* sc = pi + (long)B * I_TOK * HIDDEN;
    unsigned short* Xh  = (unsigned short*)(sc + (long)B * T * I_TOK);
    unsigned short* Xl  = Xh + X_ELEMS;
    unsigned short* WTh = Xl + X_ELEMS;
    unsigned short* WTl = WTh + W_ELEMS;

    float* out_text = (float*)d_out;                        // B*T*IMAGE_DIM
    float* out_img  = out_text + (long)B * T * IMAGE_DIM;   // B*I*TEXT_DIM

    prep_kernel<<<PREP_GRID, 256, 0, stream>>>(text, image, Wt, Wi, Xh, Xl, WTh, WTl);
    mfma_proj_kernel<<<GEMM_GRID, 256, 0, stream>>>(Xh, Xl, WTh, WTl, bt, bi, pt, pi);
    scores_kernel<<<2 * B * T, 256, 0, stream>>>(pt, pi, wa, ba, sc);
    att_kernel<<<512 + B * (I_TOK / 4), 256, 0, stream>>>(sc, image, text, out_text, out_img);
}

// Round 13
// 145.046 us; speedup vs baseline: 1.0601x; 1.0245x over previous
//
#include <hip/hip_runtime.h>
#include <math.h>

#define B 8
#define T 128
#define I_TOK 196
#define TEXT_DIM 768
#define IMAGE_DIM 1024
#define HIDDEN 512
#define EXP_SCALE 2.88539008177792681f   // 2*log2(e): exp(2x) = 2^(EXP_SCALE*x)

#if __has_builtin(__builtin_amdgcn_exp2f)
#define FAST_EXP2(x) __builtin_amdgcn_exp2f(x)
#else
#define FAST_EXP2(x) exp2f(x)
#endif
#if __has_builtin(__builtin_amdgcn_rcpf)
#define FAST_RCP(x) __builtin_amdgcn_rcpf(x)
#else
#define FAST_RCP(x) __fdividef(1.f, (x))
#endif
#if __has_builtin(__builtin_amdgcn_sched_barrier)
#define SCHED_FENCE() __builtin_amdgcn_sched_barrier(0)
#else
#define SCHED_FENCE()
#endif

typedef short bf16x8 __attribute__((ext_vector_type(8)));
typedef float f32x4 __attribute__((ext_vector_type(4)));

// ---- fragment-tiled layout geometry (R9, unchanged) -----------------------
#define KT_T (TEXT_DIM / 32)
#define KT_I (IMAGE_DIM / 32)
#define MT_T (B * T / 16)
#define MT_I (B * I_TOK / 16)
#define NT   (HIDDEN / 16)

#define XT_ELEMS (MT_T * KT_T * 512)
#define XI_ELEMS (MT_I * KT_I * 512)
#define X_ELEMS  (XT_ELEMS + XI_ELEMS)
#define WT_T_ELEMS (NT * KT_T * 512)
#define W_ELEMS (WT_T_ELEMS + NT * KT_I * 512)

#define XTILES_T (MT_T * KT_T)
#define XTILES   (XTILES_T + MT_I * KT_I)
#define WTILES_T (NT * KT_T)
#define WTILES   (WTILES_T + NT * KT_I)
#define PREP_GRID ((XTILES + WTILES) / 4)

__device__ __forceinline__ unsigned short f2bf(float x) {
    unsigned int u = __float_as_uint(x);
    unsigned int r = u + 0x7FFFu + ((u >> 16) & 1u);   // RNE
    return (unsigned short)(r >> 16);
}
__device__ __forceinline__ float bf2f(unsigned short h) {
    return __uint_as_float(((unsigned int)h) << 16);
}

// ---------------- prep v9 (R9 exact — best measured) -----------------------
__global__ __launch_bounds__(256) void prep_kernel(
        const float* __restrict__ text, const float* __restrict__ image,
        const float* __restrict__ Wt, const float* __restrict__ Wi,
        unsigned short* __restrict__ Xh, unsigned short* __restrict__ Xl,
        unsigned short* __restrict__ WTh, unsigned short* __restrict__ WTl)
{
    const int tid = threadIdx.x;
    const int lane = tid & 63, wv = tid >> 6;
    const int r16 = lane & 15, quad = lane >> 4;
    const int id = blockIdx.x * 4 + wv;

    float v[8];
    unsigned short* oh;
    unsigned short* ol;
    long dst;

    if (id < XTILES) {
        const float* X; int K, mt, kt;
        if (id < XTILES_T) { X = text; K = TEXT_DIM; mt = id / KT_T; kt = id % KT_T; }
        else { const int i2 = id - XTILES_T; X = image; K = IMAGE_DIM; mt = i2 / KT_I; kt = i2 % KT_I; }
        const float* src = X + (long)(mt * 16 + r16) * K + kt * 32 + quad * 8;
        const float4 a = *(const float4*)src;
        const float4 b = *(const float4*)(src + 4);
        v[0]=a.x; v[1]=a.y; v[2]=a.z; v[3]=a.w; v[4]=b.x; v[5]=b.y; v[6]=b.z; v[7]=b.w;
        oh = (id < XTILES_T) ? Xh : Xh + XT_ELEMS;
        ol = (id < XTILES_T) ? Xl : Xl + XT_ELEMS;
        const long tile = (id < XTILES_T) ? id : (long)(id - XTILES_T);
        dst = tile * 512 + lane * 8;
    } else {
        const int idw = id - XTILES;
        const float* W; int K, nt, kt;
        if (idw < WTILES_T) { W = Wt; K = TEXT_DIM; nt = idw / KT_T; kt = idw % KT_T; }
        else { const int i2 = idw - WTILES_T; W = Wi; K = IMAGE_DIM; nt = i2 / KT_I; kt = i2 % KT_I; }
        const float* src = W + (long)(kt * 32 + quad * 8) * HIDDEN + nt * 16 + r16;
        #pragma unroll
        for (int j = 0; j < 8; ++j) v[j] = src[(long)j * HIDDEN];
        oh = (idw < WTILES_T) ? WTh : WTh + WT_T_ELEMS;
        ol = (idw < WTILES_T) ? WTl : WTl + WT_T_ELEMS;
        const long tile = (idw < WTILES_T) ? idw : (long)(idw - WTILES_T);
        dst = tile * 512 + lane * 8;
    }

    uint4 hv, lv;
    unsigned int hh[8], ll[8];
    #pragma unroll
    for (int j = 0; j < 8; ++j) {
        hh[j] = f2bf(v[j]);
        ll[j] = f2bf(v[j] - bf2f((unsigned short)hh[j]));
    }
    hv.x = hh[0] | (hh[1] << 16); hv.y = hh[2] | (hh[3] << 16);
    hv.z = hh[4] | (hh[5] << 16); hv.w = hh[6] | (hh[7] << 16);
    lv.x = ll[0] | (ll[1] << 16); lv.y = ll[2] | (ll[3] << 16);
    lv.z = ll[4] | (ll[5] << 16); lv.w = ll[6] | (ll[7] << 16);
    *(uint4*)(oh + dst) = hv;
    *(uint4*)(ol + dst) = lv;
}

// ---------------- MFMA projections v9 (R9 exact) ---------------------------
#define GT_BLOCKS (32 * 8)
#define GI_BLOCKS (49 * 8)
#define GEMM_GRID (GT_BLOCKS + GI_BLOCKS)
#define PSTRIDE 66

__global__ __launch_bounds__(256, 2) void mfma_proj_kernel(
        const unsigned short* __restrict__ Xh, const unsigned short* __restrict__ Xl,
        const unsigned short* __restrict__ WTh, const unsigned short* __restrict__ WTl,
        const float* __restrict__ bt, const float* __restrict__ bi,
        float* __restrict__ pt, float* __restrict__ pi)
{
    __shared__ float part[32 * PSTRIDE];

    const int tid = threadIdx.x;
    const int lane = tid & 63, wv = tid >> 6;
    const int r16 = lane & 15, quad = lane >> 4;
    const int nh = wv & 1;
    const int kh = wv >> 1;

    int bid = blockIdx.x;
    const unsigned short *xh, *xl, *wh, *wl; const float* bias; float* Y;
    int ktiles;
    if (bid < GT_BLOCKS) {
        xh = Xh; xl = Xl; wh = WTh; wl = WTl; bias = bt; Y = pt; ktiles = KT_T;
    } else {
        bid -= GT_BLOCKS;
        xh = Xh + XT_ELEMS; xl = Xl + XT_ELEMS;
        wh = WTh + WT_T_ELEMS; wl = WTl + WT_T_ELEMS;
        bias = bi; Y = pi; ktiles = KT_I;
    }
    const int m0 = (bid >> 3) * 32;
    const int n0 = (bid & 7) * 64 + nh * 32;
    const int nstep = ktiles >> 1;
    const int kt0 = kh * nstep;
    const int mt0 = (bid >> 3) * 2;
    const int nt0 = (bid & 7) * 4 + nh * 2;

    const unsigned short* pa0 = xh + ((long)mt0 * ktiles + kt0) * 512 + lane * 8;
    const unsigned short* pa1 = pa0 + (long)ktiles * 512;
    const unsigned short* qa0 = xl + ((long)mt0 * ktiles + kt0) * 512 + lane * 8;
    const unsigned short* qa1 = qa0 + (long)ktiles * 512;
    const unsigned short* pb0 = wh + ((long)nt0 * ktiles + kt0) * 512 + lane * 8;
    const unsigned short* pb1 = pb0 + (long)ktiles * 512;
    const unsigned short* qb0 = wl + ((long)nt0 * ktiles + kt0) * 512 + lane * 8;
    const unsigned short* qb1 = qb0 + (long)ktiles * 512;

    f32x4 a00 = {0,0,0,0}, a01 = {0,0,0,0}, a10 = {0,0,0,0}, a11 = {0,0,0,0};

    bf16x8 Ah0 = *(const bf16x8*)(pa0);
    bf16x8 Ah1 = *(const bf16x8*)(pa1);
    bf16x8 Al0 = *(const bf16x8*)(qa0);
    bf16x8 Al1 = *(const bf16x8*)(qa1);
    bf16x8 Bh0 = *(const bf16x8*)(pb0);
    bf16x8 Bh1 = *(const bf16x8*)(pb1);
    bf16x8 Bl0 = *(const bf16x8*)(qb0);
    bf16x8 Bl1 = *(const bf16x8*)(qb1);

    for (int s = 0; s < nstep; ++s) {
        const long kn = (s + 1 < nstep) ? (long)(s + 1) * 512 : 0;
        const bf16x8 nAh0 = *(const bf16x8*)(pa0 + kn);
        const bf16x8 nAh1 = *(const bf16x8*)(pa1 + kn);
        const bf16x8 nAl0 = *(const bf16x8*)(qa0 + kn);
        const bf16x8 nAl1 = *(const bf16x8*)(qa1 + kn);
        const bf16x8 nBh0 = *(const bf16x8*)(pb0 + kn);
        const bf16x8 nBh1 = *(const bf16x8*)(pb1 + kn);
        const bf16x8 nBl0 = *(const bf16x8*)(qb0 + kn);
        const bf16x8 nBl1 = *(const bf16x8*)(qb1 + kn);
        SCHED_FENCE();

        a00 = __builtin_amdgcn_mfma_f32_16x16x32_bf16(Ah0, Bh0, a00, 0, 0, 0);
        a01 = __builtin_amdgcn_mfma_f32_16x16x32_bf16(Ah0, Bh1, a01, 0, 0, 0);
        a10 = __builtin_amdgcn_mfma_f32_16x16x32_bf16(Ah1, Bh0, a10, 0, 0, 0);
        a11 = __builtin_amdgcn_mfma_f32_16x16x32_bf16(Ah1, Bh1, a11, 0, 0, 0);
        a00 = __builtin_amdgcn_mfma_f32_16x16x32_bf16(Ah0, Bl0, a00, 0, 0, 0);
        a01 = __builtin_amdgcn_mfma_f32_16x16x32_bf16(Ah0, Bl1, a01, 0, 0, 0);
        a10 = __builtin_amdgcn_mfma_f32_16x16x32_bf16(Ah1, Bl0, a10, 0, 0, 0);
        a11 = __builtin_amdgcn_mfma_f32_16x16x32_bf16(Ah1, Bl1, a11, 0, 0, 0);
        a00 = __builtin_amdgcn_mfma_f32_16x16x32_bf16(Al0, Bh0, a00, 0, 0, 0);
        a01 = __builtin_amdgcn_mfma_f32_16x16x32_bf16(Al0, Bh1, a01, 0, 0, 0);
        a10 = __builtin_amdgcn_mfma_f32_16x16x32_bf16(Al1, Bh0, a10, 0, 0, 0);
        a11 = __builtin_amdgcn_mfma_f32_16x16x32_bf16(Al1, Bh1, a11, 0, 0, 0);
        SCHED_FENCE();

        Ah0 = nAh0; Ah1 = nAh1; Al0 = nAl0; Al1 = nAl1;
        Bh0 = nBh0; Bh1 = nBh1; Bl0 = nBl0; Bl1 = nBl1;
    }

    const int lc = nh * 32 + r16;
    if (kh == 1) {
        #pragma unroll
        for (int r = 0; r < 4; ++r) {
            part[(quad * 4 + r) * PSTRIDE + lc]           = a00[r];
            part[(quad * 4 + r) * PSTRIDE + lc + 16]      = a01[r];
            part[(quad * 4 + 16 + r) * PSTRIDE + lc]      = a10[r];
            part[(quad * 4 + 16 + r) * PSTRIDE + lc + 16] = a11[r];
        }
    }
    __syncthreads();
    if (kh == 0) {
        const int row0 = m0 + quad * 4;
        const float bv0 = bias[n0 + r16];
        const float bv1 = bias[n0 + 16 + r16];
        #pragma unroll
        for (int r = 0; r < 4; ++r) {
            const float v00 = (a00[r] + part[(quad * 4 + r) * PSTRIDE + lc]           + bv0) * EXP_SCALE;
            const float v01 = (a01[r] + part[(quad * 4 + r) * PSTRIDE + lc + 16]      + bv1) * EXP_SCALE;
            const float v10 = (a10[r] + part[(quad * 4 + 16 + r) * PSTRIDE + lc]      + bv0) * EXP_SCALE;
            const float v11 = (a11[r] + part[(quad * 4 + 16 + r) * PSTRIDE + lc + 16] + bv1) * EXP_SCALE;
            Y[(long)(row0 + r)      * HIDDEN + n0 + r16]      = FAST_EXP2(v00);
            Y[(long)(row0 + r)      * HIDDEN + n0 + 16 + r16] = FAST_EXP2(v01);
            Y[(long)(row0 + 16 + r) * HIDDEN + n0 + r16]      = FAST_EXP2(v10);
            Y[(long)(row0 + 16 + r) * HIDDEN + n0 + 16 + r16] = FAST_EXP2(v11);
        }
    }
}

// ---------------- Scores v8 (R9 exact — best measured) ---------------------
__global__ __launch_bounds__(256, 8) void scores_kernel(const float* __restrict__ pt,
        const float* __restrict__ pi, const float* __restrict__ wa,
        const float* __restrict__ ba, float* __restrict__ scores)
{
    const int blk = blockIdx.x;
    const int bt = blk >> 1;
    const int half = blk & 1;
    const int b = bt >> 7;
    const int tid = threadIdx.x;
    const int lane = tid & 63, wave = tid >> 6;

    const float* ptrow = pt + (long)bt * HIDDEN + lane * 8;
    const float4 pA = *(const float4*)ptrow;
    const float4 pB = *(const float4*)(ptrow + 4);
    float4 wA = *(const float4*)(wa + lane * 8);
    float4 wB = *(const float4*)(wa + lane * 8 + 4);

    float S = wA.x + wA.y + wA.z + wA.w + wB.x + wB.y + wB.z + wB.w;
    #pragma unroll
    for (int off = 32; off; off >>= 1) S += __shfl_down(S, off);
    const float base = S + ba[0];

    wA.x *= -2.f; wA.y *= -2.f; wA.z *= -2.f; wA.w *= -2.f;
    wB.x *= -2.f; wB.y *= -2.f; wB.z *= -2.f; wB.w *= -2.f;

    const float* pib = pi + (long)b * I_TOK * HIDDEN + lane * 8;
    const int i0 = half * 98 + wave;
    const int iend = half * 98 + 98;

    float4 ca = *(const float4*)(pib + (long)i0 * HIDDEN);
    float4 cb = *(const float4*)(pib + (long)i0 * HIDDEN + 4);

    for (int i = i0; i < iend; i += 4) {
        const int inx = (i + 4 < iend) ? (i + 4) : i;
        const float4 na = *(const float4*)(pib + (long)inx * HIDDEN);
        const float4 nb = *(const float4*)(pib + (long)inx * HIDDEN + 4);

        float acc = 0.f;
        acc = fmaf(wA.x, FAST_RCP(fmaf(pA.x, ca.x, 1.f)), acc);
        acc = fmaf(wA.y, FAST_RCP(fmaf(pA.y, ca.y, 1.f)), acc);
        acc = fmaf(wA.z, FAST_RCP(fmaf(pA.z, ca.z, 1.f)), acc);
        acc = fmaf(wA.w, FAST_RCP(fmaf(pA.w, ca.w, 1.f)), acc);
        acc = fmaf(wB.x, FAST_RCP(fmaf(pB.x, cb.x, 1.f)), acc);
        acc = fmaf(wB.y, FAST_RCP(fmaf(pB.y, cb.y, 1.f)), acc);
        acc = fmaf(wB.z, FAST_RCP(fmaf(pB.z, cb.z, 1.f)), acc);
        acc = fmaf(wB.w, FAST_RCP(fmaf(pB.w, cb.w, 1.f)), acc);

        #pragma unroll
        for (int off = 32; off; off >>= 1) acc += __shfl_down(acc, off);
        if (lane == 0) scores[(long)bt * I_TOK + i] = base + acc;
        ca = na; cb = nb;
    }
}

// ---------------- Fused attended outputs v13 -------------------------------
// R12 post-mortem: att never rewritten for occupancy since R6 — 904 blocks
// = 3.5 waves/SIMD-CU, latency-starved. v13: col-split 4x (text: 1024 blks,
// 1 float/thread) + 3x (image: 1176 blks) -> 2200 blocks ~ 8.6/CU = max
// waves/CU. Loads stay line-minimal (256B/wave = 2 lines). Softmax
// recomputed per col-split (trivial). Batch-4 loads for vmem ILP.
#define ATT_TEXT_BLOCKS (B * (T / 4) * 4)      // 1024
#define ATT_IMG_BLOCKS  (3 * B * (I_TOK / 4))  // 1176
#define ATT_GRID (ATT_TEXT_BLOCKS + ATT_IMG_BLOCKS)

__global__ __launch_bounds__(256) void att_kernel(const float* __restrict__ scores,
        const float* __restrict__ image, const float* __restrict__ text,
        float* __restrict__ out_text, float* __restrict__ out_img)
{
    __shared__ float sm[I_TOK * 4];            // 3.1 KB (softmax weights x4 rows)
    const int tid = threadIdx.x, lane = tid & 63, wave = tid >> 6;

    if (blockIdx.x < ATT_TEXT_BLOCKS) {
        const int bid = blockIdx.x;
        const int csplit = bid & 3;            // 4 x 256-col slices
        const int grp = bid >> 2;              // 0..255
        const int b = grp >> 5;
        const int t0 = (grp & 31) * 4;

        {   // wave w: softmax of score row t0+w -> sm[i*4 + w]
            const float* srow = scores + ((long)(b * T + t0 + wave)) * I_TOK;
            const float s0 = srow[lane];
            const float s1 = srow[lane + 64];
            const float s2 = srow[lane + 128];
            const float s3 = (lane < 4) ? srow[lane + 192] : -INFINITY;
            float m = fmaxf(fmaxf(s0, s1), fmaxf(s2, s3));
            #pragma unroll
            for (int off = 32; off; off >>= 1) m = fmaxf(m, __shfl_xor(m, off));
            const float e0 = __expf(s0 - m);
            const float e1 = __expf(s1 - m);
            const float e2 = __expf(s2 - m);
            const float e3 = (lane < 4) ? __expf(s3 - m) : 0.f;
            float sum = e0 + e1 + e2 + e3;
            #pragma unroll
            for (int off = 32; off; off >>= 1) sum += __shfl_xor(sum, off);
            const float inv = __fdividef(1.0f, sum);
            sm[lane * 4 + wave] = e0 * inv;
            sm[(lane + 64) * 4 + wave] = e1 * inv;
            sm[(lane + 128) * 4 + wave] = e2 * inv;
            if (lane < 4) sm[(lane + 192) * 4 + wave] = e3 * inv;
        }
        __syncthreads();

        const float* img = image + (long)b * I_TOK * IMAGE_DIM + csplit * 256 + tid;
        float a0 = 0.f, a1 = 0.f, a2 = 0.f, a3 = 0.f;

        for (int g = 0; g < 49; ++g) {         // 196 = 49*4, batch-4 loads
            const int i = g * 4;
            const float v0 = img[(long)(i + 0) * IMAGE_DIM];
            const float v1 = img[(long)(i + 1) * IMAGE_DIM];
            const float v2 = img[(long)(i + 2) * IMAGE_DIM];
            const float v3 = img[(long)(i + 3) * IMAGE_DIM];
            const float4 p0 = *(const float4*)&sm[(i + 0) * 4];
            const float4 p1 = *(const float4*)&sm[(i + 1) * 4];
            const float4 p2 = *(const float4*)&sm[(i + 2) * 4];
            const float4 p3 = *(const float4*)&sm[(i + 3) * 4];
            a0 = fmaf(p0.x, v0, a0); a1 = fmaf(p0.y, v0, a1);
            a2 = fmaf(p0.z, v0, a2); a3 = fmaf(p0.w, v0, a3);
            a0 = fmaf(p1.x, v1, a0); a1 = fmaf(p1.y, v1, a1);
            a2 = fmaf(p1.z, v1, a2); a3 = fmaf(p1.w, v1, a3);
            a0 = fmaf(p2.x, v2, a0); a1 = fmaf(p2.y, v2, a1);
            a2 = fmaf(p2.z, v2, a2); a3 = fmaf(p2.w, v2, a3);
            a0 = fmaf(p3.x, v3, a0); a1 = fmaf(p3.y, v3, a1);
            a2 = fmaf(p3.z, v3, a2); a3 = fmaf(p3.w, v3, a3);
        }
        float* o = out_text + ((long)(b * T + t0)) * IMAGE_DIM + csplit * 256 + tid;
        o[0 * IMAGE_DIM] = a0;
        o[1 * IMAGE_DIM] = a1;
        o[2 * IMAGE_DIM] = a2;
        o[3 * IMAGE_DIM] = a3;
    } else {
        const int bid = blockIdx.x - ATT_TEXT_BLOCKS;
        const int csplit = bid / (B * (I_TOK / 4));        // 0..2
        const int g2 = bid % (B * (I_TOK / 4));
        const int b = g2 / (I_TOK / 4);
        const int i0 = (g2 % (I_TOK / 4)) * 4;

        {   // wave w: softmax over t of column i0+w -> sm[t*4 + w]
            const float* sc = scores + (long)b * T * I_TOK + (i0 + wave);
            const float s0 = sc[(long)lane * I_TOK];
            const float s1 = sc[(long)(lane + 64) * I_TOK];
            float m = fmaxf(s0, s1);
            #pragma unroll
            for (int off = 32; off; off >>= 1) m = fmaxf(m, __shfl_xor(m, off));
            const float e0 = __expf(s0 - m);
            const float e1 = __expf(s1 - m);
            float sum = e0 + e1;
            #pragma unroll
            for (int off = 32; off; off >>= 1) sum += __shfl_xor(sum, off);
            const float inv = __fdividef(1.0f, sum);
            sm[lane * 4 + wave] = e0 * inv;
            sm[(lane + 64) * 4 + wave] = e1 * inv;
        }
        __syncthreads();

        const float* txt = text + (long)b * T * TEXT_DIM + csplit * 256 + tid;
        float a0 = 0.f, a1 = 0.f, a2 = 0.f, a3 = 0.f;

        for (int g = 0; g < 32; ++g) {         // 128 = 32*4, batch-4 loads
            const int t = g * 4;
            const float v0 = txt[(long)(t + 0) * TEXT_DIM];
            const float v1 = txt[(long)(t + 1) * TEXT_DIM];
            const float v2 = txt[(long)(t + 2) * TEXT_DIM];
            const float v3 = txt[(long)(t + 3) * TEXT_DIM];
            const float4 q0 = *(const float4*)&sm[(t + 0) * 4];
            const float4 q1 = *(const float4*)&sm[(t + 1) * 4];
            const float4 q2 = *(const float4*)&sm[(t + 2) * 4];
            const float4 q3 = *(const float4*)&sm[(t + 3) * 4];
            a0 = fmaf(q0.x, v0, a0); a1 = fmaf(q0.y, v0, a1);
            a2 = fmaf(q0.z, v0, a2); a3 = fmaf(q0.w, v0, a3);
            a0 = fmaf(q1.x, v1, a0); a1 = fmaf(q1.y, v1, a1);
            a2 = fmaf(q1.z, v1, a2); a3 = fmaf(q1.w, v1, a3);
            a0 = fmaf(q2.x, v2, a0); a1 = fmaf(q2.y, v2, a1);
            a2 = fmaf(q2.z, v2, a2); a3 = fmaf(q2.w, v2, a3);
            a0 = fmaf(q3.x, v3, a0); a1 = fmaf(q3.y, v3, a1);
            a2 = fmaf(q3.z, v3, a2); a3 = fmaf(q3.w, v3, a3);
        }
        float* o = out_img + ((long)b * I_TOK + i0) * TEXT_DIM + csplit * 256 + tid;
        o[0 * TEXT_DIM] = a0;
        o[1 * TEXT_DIM] = a1;
        o[2 * TEXT_DIM] = a2;
        o[3 * TEXT_DIM] = a3;
    }
}

extern "C" void kernel_launch(void* const* d_in, const int* in_sizes, int n_in,
                              void* d_out, int out_size, void* d_ws, size_t ws_size,
                              hipStream_t stream) {
    const float* text  = (const float*)d_in[0];
    const float* image = (const float*)d_in[1];
    const float* Wt    = (const float*)d_in[2];
    const float* bt    = (const float*)d_in[3];
    const float* Wi    = (const float*)d_in[4];
    const float* bi    = (const float*)d_in[5];
    const float* wa    = (const float*)d_in[6];
    const float* ba    = (const float*)d_in[7];

    float* pt = (float*)d_ws;                       // Et = exp2-transformed
    float* pi = pt + (long)B * T * HIDDEN;          // Ei
    float* sc = pi + (long)B * I_TOK * HIDDEN;
    unsigned short* Xh  = (unsigned short*)(sc + (long)B * T * I_TOK);
    unsigned short* Xl  = Xh + X_ELEMS;
    unsigned short* WTh = Xl + X_ELEMS;
    unsigned short* WTl = WTh + W_ELEMS;

    float* out_text = (float*)d_out;                        // B*T*IMAGE_DIM
    float* out_img  = out_text + (long)B * T * IMAGE_DIM;   // B*I*TEXT_DIM

    prep_kernel<<<PREP_GRID, 256, 0, stream>>>(text, image, Wt, Wi, Xh, Xl, WTh, WTl);
    mfma_proj_kernel<<<GEMM_GRID, 256, 0, stream>>>(Xh, Xl, WTh, WTl, bt, bi, pt, pi);
    scores_kernel<<<2 * B * T, 256, 0, stream>>>(pt, pi, wa, ba, sc);
    att_kernel<<<ATT_GRID, 256, 0, stream>>>(sc, image, text, out_text, out_img);
}